// Round 9
// baseline (125.246 us; speedup 1.0000x reference)
//
#include <hip/hip_runtime.h>
#include <hip/hip_bf16.h>

#define SQ 2048
#define NH 32
#define DH 128
#define NK 256
#define SCALE 0.08838834764831845f
#define LOG2E 1.4426950408889634f

typedef __attribute__((ext_vector_type(8))) __bf16 bf16x8;
typedef __attribute__((ext_vector_type(4))) float floatx4;

// element strides (u16)
#define QS_STRIDE 136   // Q staged rows, 272 B (phase-0 overlay in pbuf region)
#define VB_STRIDE 72    // V transposed [d][k_local]; 144 B rows

// LDS (bytes): pbuf [32][512B] XOR-swizzled 16384 | V^T dbuf0/1 2x18432 | stats
#define OFF_DB0  16384
#define OFF_DB1  (OFF_DB0 + 18432)   // 34816
#define OFF_RED  (OFF_DB1 + 18432)   // 53248: 128 floats (m_w)
#define OFF_RED2 (OFF_RED + 512)     // 53760: 128 floats (p_w)
#define SMEM_SZ  54272               // x3 = 162816 <= 163840 -> 3 blocks/CU

#define SCHED_PIN() __builtin_amdgcn_sched_barrier(0)

// XOR swizzle for pbuf rows (16B granule, bijective within a 512B row)
__device__ __forceinline__ int swz(int row) { return ((row ^ (row >> 3)) & 7) << 4; }

__device__ __forceinline__ unsigned pk_bf16(float a, float b) {
  union { __hip_bfloat162 h2; unsigned u; } c;
  c.h2 = __float22bfloat162_rn(make_float2(a, b));
  return c.u;
}

__device__ __forceinline__ float fast_exp2(float x) {
#if __has_builtin(__builtin_amdgcn_exp2f)
  return __builtin_amdgcn_exp2f(x);
#else
  return exp2f(x);
#endif
}

template <int CTRL>
__device__ __forceinline__ float dpp_rot(float x) {
  int i = __builtin_bit_cast(int, x);
  i = __builtin_amdgcn_mov_dpp(i, CTRL, 0xF, 0xF, true);
  return __builtin_bit_cast(float, i);
}
#define RED16_MAX(v) { v = fmaxf(v, dpp_rot<0x121>(v)); v = fmaxf(v, dpp_rot<0x122>(v)); \
                       v = fmaxf(v, dpp_rot<0x124>(v)); v = fmaxf(v, dpp_rot<0x128>(v)); }
#define RED16_SUM(v) { v += dpp_rot<0x121>(v); v += dpp_rot<0x122>(v); \
                       v += dpp_rot<0x124>(v); v += dpp_rot<0x128>(v); }

// ---- pre-pass: kv fp32 [4096][2][128] -> bf16 in d_ws ----
__global__ __launch_bounds__(256) void kv_to_bf16(const float* __restrict__ kv,
                                                  unsigned short* __restrict__ kvb) {
  int i = blockIdx.x * 256 + threadIdx.x;
  float4 f = ((const float4*)kv)[i];
  uint2 o = { pk_bf16(f.x, f.y), pk_bf16(f.z, f.w) };
  ((uint2*)kvb)[i] = o;
}

// K B-fragments, DIRECT to registers (no LDS for K): lane (quad,l16) holds
// B[k=quad*8+j][col=l16] = K[tkg[c*64+wave*16+l16]][ks*32+quad*8+j] — 16
// contiguous bytes; 4 quads of a row share one 64B line (coalesced). No
// cross-wave sharing needed -> GEMM1 needs no barriers at all.
struct KB { bf16x8 b[4]; };   // 16 VGPRs

__device__ __forceinline__ KB kb_load(const unsigned short* __restrict__ kvb,
                                      int idx, int quad) {
  const unsigned short* kp = kvb + (size_t)idx * 256 + quad * 8;
  KB k;
#pragma unroll
  for (int ks = 0; ks < 4; ks++) k.b[ks] = *(const bf16x8*)(kp + ks * 32);
  return k;
}

__device__ __forceinline__ void gemm_reg(const KB& kb, const bf16x8 af[2][4],
                                         floatx4& a0, floatx4& a1) {
  a0 = (floatx4){0.f, 0.f, 0.f, 0.f};
  a1 = (floatx4){0.f, 0.f, 0.f, 0.f};
  __builtin_amdgcn_s_setprio(1);
#pragma unroll
  for (int ks = 0; ks < 4; ks++) {
    a0 = __builtin_amdgcn_mfma_f32_16x16x32_bf16(af[0][ks], kb.b[ks], a0, 0, 0, 0);
    a1 = __builtin_amdgcn_mfma_f32_16x16x32_bf16(af[1][ks], kb.b[ks], a1, 0, 0, 0);
  }
  __builtin_amdgcn_s_setprio(0);
}

struct VR { uint4 a, b, c, d; };

// V gather: 4 dg-lanes of a row share one 64B line (coalesced)
__device__ __forceinline__ VR v_load(const unsigned short* __restrict__ kvb,
                                     const int* __restrict__ tkg, int c, int tid) {
  int rg = tid & 15, dg = tid >> 4;
  int r0 = rg * 4, d0 = dg * 8;
  int4 i4 = *(const int4*)&tkg[c * 64 + r0];
  VR v;
  v.a = *(const uint4*)(kvb + (size_t)i4.x * 256 + 128 + d0);
  v.b = *(const uint4*)(kvb + (size_t)i4.y * 256 + 128 + d0);
  v.c = *(const uint4*)(kvb + (size_t)i4.z * 256 + 128 + d0);
  v.d = *(const uint4*)(kvb + (size_t)i4.w * 256 + 128 + d0);
  return v;
}

__device__ __forceinline__ void v_write(unsigned short* vbuf, const VR& v, int tid) {
  int rg = tid & 15, dg = tid >> 4;
  int r0 = rg * 4, d0 = dg * 8;
  const unsigned* pa = (const unsigned*)&v.a;
  const unsigned* pb = (const unsigned*)&v.b;
  const unsigned* pc = (const unsigned*)&v.c;
  const unsigned* pd = (const unsigned*)&v.d;
#pragma unroll
  for (int w = 0; w < 4; w++) {
    unsigned lo01 = __builtin_amdgcn_perm(pb[w], pa[w], 0x05040100u);
    unsigned lo23 = __builtin_amdgcn_perm(pd[w], pc[w], 0x05040100u);
    unsigned hi01 = __builtin_amdgcn_perm(pb[w], pa[w], 0x07060302u);
    unsigned hi23 = __builtin_amdgcn_perm(pd[w], pc[w], 0x07060302u);
    uint2 lo = { lo01, lo23 }, hi = { hi01, hi23 };
    *(uint2*)&vbuf[(d0 + 2 * w) * VB_STRIDE + r0] = lo;
    *(uint2*)&vbuf[(d0 + 2 * w + 1) * VB_STRIDE + r0] = hi;
  }
}

__device__ __forceinline__ void pv_chunk(const char* pbuf,
                                         const unsigned short* vbuf, int c,
                                         int wave, int quad, int l16,
                                         floatx4 oacc[2][2]) {
  __builtin_amdgcn_s_setprio(1);
#pragma unroll
  for (int ks = 0; ks < 2; ks++) {
    int kof = (c * 64 + ks * 32 + quad * 8) * 2;   // bytes within P row
    bf16x8 a0 = *(const bf16x8*)(pbuf + ((l16 * 512 + kof) ^ swz(l16)));
    bf16x8 a1 = *(const bf16x8*)(pbuf + (((16 + l16) * 512 + kof) ^ swz(16 + l16)));
    int kl = ks * 32 + quad * 8;
    bf16x8 b0 = *(const bf16x8*)&vbuf[(wave * 32 + l16) * VB_STRIDE + kl];
    bf16x8 b1 = *(const bf16x8*)&vbuf[(wave * 32 + 16 + l16) * VB_STRIDE + kl];
    oacc[0][0] = __builtin_amdgcn_mfma_f32_16x16x32_bf16(a0, b0, oacc[0][0], 0, 0, 0);
    oacc[0][1] = __builtin_amdgcn_mfma_f32_16x16x32_bf16(a0, b1, oacc[0][1], 0, 0, 0);
    oacc[1][0] = __builtin_amdgcn_mfma_f32_16x16x32_bf16(a1, b0, oacc[1][0], 0, 0, 0);
    oacc[1][1] = __builtin_amdgcn_mfma_f32_16x16x32_bf16(a1, b1, oacc[1][1], 0, 0, 0);
  }
  __builtin_amdgcn_s_setprio(0);
}

__global__ __launch_bounds__(256, 3) void sparse_attn_kernel(
    const float* __restrict__ q, const unsigned short* __restrict__ kvb,
    const float* __restrict__ sink, const int* __restrict__ topk,
    float* __restrict__ out) {
  __shared__ __align__(16) char smem[SMEM_SZ];
  char* pbuf = smem;                                         // P [32][512B] swizzled
  unsigned short* qs  = (unsigned short*)smem;               // phase-0 overlay
  unsigned short* db0 = (unsigned short*)(smem + OFF_DB0);   // V^T double buffer
  unsigned short* db1 = (unsigned short*)(smem + OFF_DB1);
  float* red  = (float*)(smem + OFF_RED);    // m_w[wave*32 + h]
  float* red2 = (float*)(smem + OFF_RED2);   // p_w[wave*32 + h]

  const int tid = threadIdx.x;
  const int s = blockIdx.x;
  const int wave = tid >> 6;
  const int lane = tid & 63;
  const int quad = lane >> 4;
  const int l16 = lane & 15;
  const int* tkg = topk + (size_t)s * NK;
  const int nrow = wave * 16 + l16;

  // ---- Phase 0: per-lane K row indices, K0/K1 B-frags to regs, Q staged ----
  int kidx[4];
#pragma unroll
  for (int c = 0; c < 4; c++) kidx[c] = tkg[c * 64 + nrow];
  KB b0 = kb_load(kvb, kidx[0], quad);
  KB b1 = kb_load(kvb, kidx[1], quad);
  SCHED_PIN();

  float snk[2][4];
#pragma unroll
  for (int mt = 0; mt < 2; mt++)
#pragma unroll
    for (int r = 0; r < 4; r++)
      snk[mt][r] = sink[mt * 16 + quad * 4 + r] * LOG2E;

  {  // Q stage, pre-scaled by SCALE*log2(e): softmax runs in exp2 domain
    const float QSC = SCALE * LOG2E;
    const float* qp = q + (size_t)s * (NH * DH);
    int h = tid >> 3, d0 = (tid & 7) * 16;
    const float4* src = (const float4*)(qp + h * DH + d0);
    float4 f0 = src[0], f1 = src[1], f2 = src[2], f3 = src[3];
    uint4 o0 = { pk_bf16(f0.x * QSC, f0.y * QSC), pk_bf16(f0.z * QSC, f0.w * QSC),
                 pk_bf16(f1.x * QSC, f1.y * QSC), pk_bf16(f1.z * QSC, f1.w * QSC) };
    uint4 o1 = { pk_bf16(f2.x * QSC, f2.y * QSC), pk_bf16(f2.z * QSC, f2.w * QSC),
                 pk_bf16(f3.x * QSC, f3.y * QSC), pk_bf16(f3.z * QSC, f3.w * QSC) };
    *(uint4*)&qs[h * QS_STRIDE + d0] = o0;
    *(uint4*)&qs[h * QS_STRIDE + d0 + 8] = o1;
  }
  __syncthreads();  // qs visible

  // Hoist Q A-fragments (qs dead afterwards; pbuf reuses the space post-barrier)
  bf16x8 afrag[2][4];
#pragma unroll
  for (int mt = 0; mt < 2; mt++)
#pragma unroll
    for (int ks = 0; ks < 4; ks++)
      afrag[mt][ks] =
          *(const bf16x8*)&qs[(mt * 16 + l16) * QS_STRIDE + ks * 32 + quad * 8];

  // ---- Phase 1: GEMM1 entirely in registers — ZERO barriers, waves drift ----
  floatx4 sc[4][2];
  KB b2 = kb_load(kvb, kidx[2], quad);
  SCHED_PIN();
  gemm_reg(b0, afrag, sc[0][0], sc[0][1]);
  KB b3 = kb_load(kvb, kidx[3], quad);
  SCHED_PIN();
  gemm_reg(b1, afrag, sc[1][0], sc[1][1]);
  VR v0 = v_load(kvb, tkg, 0, tid);
  SCHED_PIN();
  gemm_reg(b2, afrag, sc[2][0], sc[2][1]);
  VR v1 = v_load(kvb, tkg, 1, tid);
  SCHED_PIN();
  gemm_reg(b3, afrag, sc[3][0], sc[3][1]);
  v_write(db0, v0, tid);   // V^T region untouched so far; pbuf barrier covers reads

  // ---- Phase 2: softmax, flash-style single stats exchange ----
  float mh[2][4];
#pragma unroll
  for (int mt = 0; mt < 2; mt++)
#pragma unroll
    for (int r = 0; r < 4; r++) {
      float v = fmaxf(fmaxf(sc[0][mt][r], sc[1][mt][r]),
                      fmaxf(sc[2][mt][r], sc[3][mt][r]));
      RED16_MAX(v);
      mh[mt][r] = v;
    }
  float ps[2][4];
#pragma unroll
  for (int mt = 0; mt < 2; mt++)
#pragma unroll
    for (int r = 0; r < 4; r++) {
      float acc = 0.f;
#pragma unroll
      for (int c = 0; c < 4; c++) {
        float e = fast_exp2(sc[c][mt][r] - mh[mt][r]);
        sc[c][mt][r] = e;
        acc += e;
      }
      RED16_SUM(acc);
      ps[mt][r] = acc;
    }
  if (l16 == 0) {
#pragma unroll
    for (int mt = 0; mt < 2; mt++)
#pragma unroll
      for (int r = 0; r < 4; r++) {
        red[wave * 32 + mt * 16 + quad * 4 + r]  = mh[mt][r];
        red2[wave * 32 + mt * 16 + quad * 4 + r] = ps[mt][r];
      }
  }
  __syncthreads();  // stats visible (first barrier since phase 0)
  VR v2 = v_load(kvb, tkg, 2, tid);   // issue under stats math
  SCHED_PIN();
  float inv[2][4], sf[2][4];
#pragma unroll
  for (int mt = 0; mt < 2; mt++)
#pragma unroll
    for (int r = 0; r < 4; r++) {
      int h = mt * 16 + quad * 4 + r;
      float M = snk[mt][r];
#pragma unroll
      for (int w = 0; w < 4; w++) M = fmaxf(M, red[w * 32 + h]);
      float dd = fast_exp2(snk[mt][r] - M);
#pragma unroll
      for (int w = 0; w < 4; w++)
        dd += red2[w * 32 + h] * fast_exp2(red[w * 32 + h] - M);
      inv[mt][r] = 1.0f / dd;
      sf[mt][r] = fast_exp2(mh[mt][r] - M);   // rescale local->global
    }
  // write P = e_local * sf (bf16, unnormalized) to pbuf [head][col], swizzled
#pragma unroll
  for (int c = 0; c < 4; c++)
#pragma unroll
    for (int mt = 0; mt < 2; mt++) {
      int col = c * 64 + wave * 16 + l16;
      unsigned p01 = pk_bf16(sc[c][mt][0] * sf[mt][0], sc[c][mt][1] * sf[mt][1]);
      unsigned p23 = pk_bf16(sc[c][mt][2] * sf[mt][2], sc[c][mt][3] * sf[mt][3]);
      unsigned short vals[4] = { (unsigned short)p01, (unsigned short)(p01 >> 16),
                                 (unsigned short)p23, (unsigned short)(p23 >> 16) };
#pragma unroll
      for (int j = 0; j < 4; j++) {
        int h = mt * 16 + quad * 4 + j;
        *(unsigned short*)(pbuf + ((h * 512 + col * 2) ^ swz(h))) = vals[j];
      }
    }
  __syncthreads();  // pbuf + V0(db0) visible

  // ---- Phase 3: O = P V, double-buffered V^T: ONE barrier per chunk ----
  floatx4 oacc[2][2];
#pragma unroll
  for (int mt = 0; mt < 2; mt++)
#pragma unroll
    for (int nt = 0; nt < 2; nt++)
      oacc[mt][nt] = (floatx4){0.f, 0.f, 0.f, 0.f};

  // pv0: read db0 | write v1->db1 | issue v3
  VR v3 = v_load(kvb, tkg, 3, tid);
  SCHED_PIN();
  pv_chunk(pbuf, db0, 0, wave, quad, l16, oacc);
  v_write(db1, v1, tid);
  __syncthreads();

  // pv1: read db1 | write v2->db0
  pv_chunk(pbuf, db1, 1, wave, quad, l16, oacc);
  v_write(db0, v2, tid);
  __syncthreads();

  // pv2: read db0 | write v3->db1
  pv_chunk(pbuf, db0, 2, wave, quad, l16, oacc);
  v_write(db1, v3, tid);
  __syncthreads();

  // pv3: read db1
  pv_chunk(pbuf, db1, 3, wave, quad, l16, oacc);

  // ---- Phase 4: epilogue ----
  {
    float* op = out + (size_t)s * (NH * DH);
#pragma unroll
    for (int mt = 0; mt < 2; mt++)
#pragma unroll
      for (int nt = 0; nt < 2; nt++)
#pragma unroll
        for (int r4 = 0; r4 < 4; r4++) {
          int h = mt * 16 + quad * 4 + r4;
          int d = wave * 32 + nt * 16 + l16;
          op[h * DH + d] = oacc[mt][nt][r4] * inv[mt][r4];
        }
  }
}

extern "C" void kernel_launch(void* const* d_in, const int* in_sizes, int n_in,
                              void* d_out, int out_size, void* d_ws, size_t ws_size,
                              hipStream_t stream) {
  (void)in_sizes; (void)n_in; (void)out_size; (void)ws_size;
  const float* q    = (const float*)d_in[0];
  const float* kv   = (const float*)d_in[1];
  const float* sink = (const float*)d_in[2];
  const int*   topk = (const int*)d_in[3];
  float* out = (float*)d_out;
  unsigned short* kvb = (unsigned short*)d_ws;  // 2 MB bf16 KV

  kv_to_bf16<<<dim3(1024), dim3(256), 0, stream>>>(kv, kvb);
  sparse_attn_kernel<<<dim3(SQ), dim3(256), 0, stream>>>(q, kvb, sink, topk, out);
}